// Round 1
// baseline (204.071 us; speedup 1.0000x reference)
//
#include <hip/hip_runtime.h>

// CenterLoss: mean over B rows of clip(||x_b - centers[label_b]||^2, 1e-12, 1e12)
// labels arrive as exact one-hot fp32 rows -> dense dot == gather (bit-exact).
// Memory-bound: ~95 MB traffic, roofline ~15 us @ 6.3 TB/s.

#define BATCH 8192
#define NUM_CLASSES 751
#define FEAT_DIM 2048

__global__ __launch_bounds__(256) void center_loss_kernel(
    const float* __restrict__ x,
    const float* __restrict__ labels,
    const float* __restrict__ centers,
    float* __restrict__ accum)
{
    const int row = blockIdx.x;
    const int tid = threadIdx.x;

    // ---- Phase 1: find the one-hot index (coalesced scan of 751 floats) ----
    __shared__ int s_idx;
    const float* lrow = labels + (size_t)row * NUM_CLASSES;
    #pragma unroll
    for (int c = tid; c < NUM_CLASSES; c += 256) {
        if (lrow[c] > 0.5f) s_idx = c;   // exactly one thread writes
    }
    __syncthreads();
    const int idx = s_idx;

    // ---- Phase 2: squared distance, 2 x float4 per thread (2048 floats) ----
    const float4* __restrict__ xrow = (const float4*)(x + (size_t)row * FEAT_DIM);
    const float4* __restrict__ crow = (const float4*)(centers + (size_t)idx * FEAT_DIM);

    float sum = 0.0f;
    #pragma unroll
    for (int i = 0; i < 2; ++i) {
        const int j = tid + i * 256;
        float4 xv = xrow[j];
        float4 cv = crow[j];
        float dx = xv.x - cv.x;
        float dy = xv.y - cv.y;
        float dz = xv.z - cv.z;
        float dw = xv.w - cv.w;
        sum += dx * dx + dy * dy + dz * dz + dw * dw;
    }

    // ---- wave-64 shuffle reduction ----
    #pragma unroll
    for (int off = 32; off > 0; off >>= 1)
        sum += __shfl_down(sum, off, 64);

    __shared__ float s_part[4];
    const int wave = tid >> 6;
    const int lane = tid & 63;
    if (lane == 0) s_part[wave] = sum;
    __syncthreads();

    if (tid == 0) {
        float ps = s_part[0] + s_part[1] + s_part[2] + s_part[3];
        ps = fminf(fmaxf(ps, 1e-12f), 1e12f);   // clip
        atomicAdd(accum, ps);                   // device-scope by default
    }
}

__global__ void finalize_kernel(const float* __restrict__ accum,
                                float* __restrict__ out)
{
    out[0] = accum[0] * (1.0f / (float)BATCH);
}

extern "C" void kernel_launch(void* const* d_in, const int* in_sizes, int n_in,
                              void* d_out, int out_size, void* d_ws, size_t ws_size,
                              hipStream_t stream)
{
    const float* x       = (const float*)d_in[0];
    const float* labels  = (const float*)d_in[1];
    const float* centers = (const float*)d_in[2];
    float* out   = (float*)d_out;
    float* accum = (float*)d_ws;

    // d_ws is poisoned to 0xAA before every launch -> zero the accumulator.
    hipMemsetAsync(accum, 0, sizeof(float), stream);

    center_loss_kernel<<<BATCH, 256, 0, stream>>>(x, labels, centers, accum);
    finalize_kernel<<<1, 1, 0, stream>>>(accum, out);
}

// Round 2
// 115.934 us; speedup vs baseline: 1.7602x; 1.7602x over previous
//
#include <hip/hip_runtime.h>

// CenterLoss: mean over B rows of clip(||x_b - centers[label_b]||^2, 1e-12, 1e12)
// labels are exact one-hot fp32 rows -> dense dot == row gather (bit-exact).
//
// R1 lesson: 8192 atomicAdds to ONE address serialized at the TCC (~32 cyc each
// = 110 us). R2: per-block partial store to d_ws (no atomics, no memset), then
// a single-block tree reduction. x-row loads prefetched before the label scan
// so the two HBM round-trips overlap.

#define BATCH 8192
#define NUM_CLASSES 751
#define FEAT_DIM 2048

__global__ __launch_bounds__(256) void center_loss_kernel(
    const float* __restrict__ x,
    const float* __restrict__ labels,
    const float* __restrict__ centers,
    float* __restrict__ partials)
{
    const int row = blockIdx.x;
    const int tid = threadIdx.x;

    // ---- Prefetch x row (independent of labels) to overlap HBM latency ----
    const float4* __restrict__ xrow = (const float4*)(x + (size_t)row * FEAT_DIM);
    float4 xv0 = xrow[tid];
    float4 xv1 = xrow[tid + 256];

    // ---- Find the one-hot index (coalesced scan of 751 floats) ----
    __shared__ int s_idx;
    const float* lrow = labels + (size_t)row * NUM_CLASSES;
    #pragma unroll
    for (int c = tid; c < NUM_CLASSES; c += 256) {
        if (lrow[c] > 0.5f) s_idx = c;   // exactly one thread writes
    }
    __syncthreads();
    const int idx = s_idx;

    // ---- Gather center row and accumulate squared distance ----
    const float4* __restrict__ crow = (const float4*)(centers + (size_t)idx * FEAT_DIM);
    float4 cv0 = crow[tid];
    float4 cv1 = crow[tid + 256];

    float dx = xv0.x - cv0.x, dy = xv0.y - cv0.y, dz = xv0.z - cv0.z, dw = xv0.w - cv0.w;
    float sum = dx * dx + dy * dy + dz * dz + dw * dw;
    dx = xv1.x - cv1.x; dy = xv1.y - cv1.y; dz = xv1.z - cv1.z; dw = xv1.w - cv1.w;
    sum += dx * dx + dy * dy + dz * dz + dw * dw;

    // ---- wave-64 shuffle reduction ----
    #pragma unroll
    for (int off = 32; off > 0; off >>= 1)
        sum += __shfl_down(sum, off, 64);

    __shared__ float s_part[4];
    const int wave = tid >> 6;
    const int lane = tid & 63;
    if (lane == 0) s_part[wave] = sum;
    __syncthreads();

    if (tid == 0) {
        float ps = s_part[0] + s_part[1] + s_part[2] + s_part[3];
        ps = fminf(fmaxf(ps, 1e-12f), 1e12f);   // clip
        partials[row] = ps;                      // deterministic store, no atomic
    }
}

// Reduce 8192 partials (32 KB, L2-hot) -> mean. One block, 256 threads.
__global__ __launch_bounds__(256) void reduce_kernel(
    const float* __restrict__ partials,
    float* __restrict__ out)
{
    const int tid = threadIdx.x;
    const float4* __restrict__ p4 = (const float4*)partials;  // 2048 float4s

    float sum = 0.0f;
    #pragma unroll
    for (int k = 0; k < 8; ++k) {
        float4 v = p4[tid + 256 * k];
        sum += v.x + v.y + v.z + v.w;
    }

    #pragma unroll
    for (int off = 32; off > 0; off >>= 1)
        sum += __shfl_down(sum, off, 64);

    __shared__ float s_part[4];
    const int wave = tid >> 6;
    const int lane = tid & 63;
    if (lane == 0) s_part[wave] = sum;
    __syncthreads();

    if (tid == 0) {
        float total = s_part[0] + s_part[1] + s_part[2] + s_part[3];
        out[0] = total * (1.0f / (float)BATCH);
    }
}

extern "C" void kernel_launch(void* const* d_in, const int* in_sizes, int n_in,
                              void* d_out, int out_size, void* d_ws, size_t ws_size,
                              hipStream_t stream)
{
    const float* x       = (const float*)d_in[0];
    const float* labels  = (const float*)d_in[1];
    const float* centers = (const float*)d_in[2];
    float* out      = (float*)d_out;
    float* partials = (float*)d_ws;   // 8192 floats, every slot overwritten

    center_loss_kernel<<<BATCH, 256, 0, stream>>>(x, labels, centers, partials);
    reduce_kernel<<<1, 256, 0, stream>>>(partials, out);
}